// Round 1
// baseline (302.362 us; speedup 1.0000x reference)
//
#include <hip/hip_runtime.h>

// FilterInterpolation: out[b,ch,y,x] = mask * sum_{r,c in 5x5} W5[r][c] *
//     img[b,ch, clip(iyT+r), clip(ixL+c)]
// where W5 groups the 16 adaptive-filter taps' bilinear weights by grid point
// (64 gathers/channel -> 25). Exact regrouping of the reference math.

#define BB 4
#define CC 3
#define HH 544
#define WW 960

__global__ __launch_bounds__(256) void filt_interp_kernel(
    const float* __restrict__ img,   // (B,3,H,W)
    const float* __restrict__ flow,  // (B,2,H,W)
    const float* __restrict__ filt,  // (B,16,H,W)
    float* __restrict__ out)         // (B,3,H,W)
{
    const int HW = HH * WW;
    int gid = blockIdx.x * 256 + threadIdx.x;
    if (gid >= BB * HW) return;

    int x = gid % WW;
    int t = gid / WW;
    int y = t % HH;
    int b = t / HH;
    int pix = y * WW + x;

    float fx = flow[(b * 2 + 0) * HW + pix];
    float fy = flow[(b * 2 + 1) * HW + pix];
    float x2 = (float)x + fx;
    float y2 = (float)y + fy;
    bool m = (x2 >= 0.0f) && (y2 >= 0.0f) &&
             (x2 <= (float)(WW - 1)) && (y2 <= (float)(HH - 1)) &&
             (fabsf(fx) < (float)WW * 0.5f) && (fabsf(fy) < (float)HH * 0.5f);
    float x2c = fminf(fmaxf(x2, 0.0f), (float)(WW - 1));
    float y2c = fminf(fmaxf(y2, 0.0f), (float)(HH - 1));
    int ix = (int)floorf(x2c);
    int iy = (int)floorf(y2c);
    float alpha = x2c - (float)ix;
    float beta  = y2c - (float)iy;
    int ixL = ix - 1;   // ix + 1 - fs/2
    int iyT = iy - 1;
    float wa = (1.0f - alpha) * (1.0f - beta);
    float wb = alpha * (1.0f - beta);
    float wc = (1.0f - alpha) * beta;
    float wd = alpha * beta;

    // Build the 5x5 combined weights from the 16 filter taps.
    float W5[5][5];
#pragma unroll
    for (int r = 0; r < 5; r++)
#pragma unroll
        for (int c = 0; c < 5; c++) W5[r][c] = 0.0f;

    const float* fp = filt + (size_t)b * 16 * HW + pix;
#pragma unroll
    for (int j = 0; j < 4; j++) {
#pragma unroll
        for (int i = 0; i < 4; i++) {
            float w3 = fp[(j * 4 + i) * HW];
            W5[j][i]         += wa * w3;
            W5[j][i + 1]     += wb * w3;
            W5[j + 1][i]     += wc * w3;
            W5[j + 1][i + 1] += wd * w3;
        }
    }

    int cx[5], ry[5];
#pragma unroll
    for (int k = 0; k < 5; k++) {
        cx[k] = min(max(ixL + k, 0), WW - 1);
        ry[k] = min(max(iyT + k, 0), HH - 1);
    }

    float mf = m ? 1.0f : 0.0f;
#pragma unroll
    for (int ch = 0; ch < 3; ch++) {
        const float* ib = img + (size_t)(b * 3 + ch) * HW;
        float acc = 0.0f;
#pragma unroll
        for (int r = 0; r < 5; r++) {
            const float* rowp = ib + (size_t)ry[r] * WW;
#pragma unroll
            for (int c = 0; c < 5; c++) acc += W5[r][c] * rowp[cx[c]];
        }
        out[(size_t)(b * 3 + ch) * HW + pix] = acc * mf;
    }
}

extern "C" void kernel_launch(void* const* d_in, const int* in_sizes, int n_in,
                              void* d_out, int out_size, void* d_ws, size_t ws_size,
                              hipStream_t stream) {
    const float* img  = (const float*)d_in[0];
    const float* flow = (const float*)d_in[1];
    const float* filt = (const float*)d_in[2];
    float* out = (float*)d_out;
    int n = BB * HH * WW;                 // one thread per (b,y,x) = 2,088,960
    int blocks = (n + 255) / 256;         // 8160
    filt_interp_kernel<<<blocks, 256, 0, stream>>>(img, flow, filt, out);
}

// Round 2
// 286.760 us; speedup vs baseline: 1.0544x; 1.0544x over previous
//
#include <hip/hip_runtime.h>

// FilterInterpolation, round 2.
// out[b,ch,y,x] = mask * sum_{r,c in 5x5} W5[r][c] * img[b,ch, clip(iyT+r), clip(ixL+c)]
// W5 groups the 16 taps' bilinear weights by grid point (exact regrouping).
//
// R1 was latency-bound (VALUBusy 13%, HBM 14%, occ 31%): 96 VMEM/thread,
// dominated by 75 scattered dword gathers. R2: pre-pass repacks img to
// channel-interleaved (B,H,W,4) float4 in d_ws so one float4 gather serves
// all 3 channels -> 25 gathers/thread, 46 VMEM total.

#define BB 4
#define CC 3
#define HH 544
#define WW 960
#define HW (HH * WW)

__global__ __launch_bounds__(256) void repack_img_kernel(
    const float* __restrict__ img,   // (B,3,H,W)
    float4* __restrict__ pk)         // (B,H,W,4)
{
    int gid = blockIdx.x * 256 + threadIdx.x;
    if (gid >= BB * HW) return;
    int pix = gid % HW;
    int b   = gid / HW;
    const float* ib = img + (size_t)b * 3 * HW + pix;
    float4 v;
    v.x = ib[0];
    v.y = ib[HW];
    v.z = ib[2 * HW];
    v.w = 0.0f;
    pk[gid] = v;
}

__global__ __launch_bounds__(256) void filt_interp_kernel(
    const float4* __restrict__ pk,   // (B,H,W,4) channel-interleaved img
    const float* __restrict__ flow,  // (B,2,H,W)
    const float* __restrict__ filt,  // (B,16,H,W)
    float* __restrict__ out)         // (B,3,H,W)
{
    int gid = blockIdx.x * 256 + threadIdx.x;
    if (gid >= BB * HW) return;

    int x = gid % WW;
    int t = gid / WW;
    int y = t % HH;
    int b = t / HH;
    int pix = y * WW + x;

    float fx = flow[(b * 2 + 0) * HW + pix];
    float fy = flow[(b * 2 + 1) * HW + pix];
    float x2 = (float)x + fx;
    float y2 = (float)y + fy;
    bool m = (x2 >= 0.0f) && (y2 >= 0.0f) &&
             (x2 <= (float)(WW - 1)) && (y2 <= (float)(HH - 1)) &&
             (fabsf(fx) < (float)WW * 0.5f) && (fabsf(fy) < (float)HH * 0.5f);
    float x2c = fminf(fmaxf(x2, 0.0f), (float)(WW - 1));
    float y2c = fminf(fmaxf(y2, 0.0f), (float)(HH - 1));
    int ix = (int)floorf(x2c);
    int iy = (int)floorf(y2c);
    float alpha = x2c - (float)ix;
    float beta  = y2c - (float)iy;
    int ixL = ix - 1;   // ix + 1 - fs/2
    int iyT = iy - 1;
    float wa = (1.0f - alpha) * (1.0f - beta);
    float wb = alpha * (1.0f - beta);
    float wc = (1.0f - alpha) * beta;
    float wd = alpha * beta;

    float mf = m ? 1.0f : 0.0f;

    // Build the 5x5 combined weights from the 16 filter taps (mask folded in).
    float W5[5][5];
#pragma unroll
    for (int r = 0; r < 5; r++)
#pragma unroll
        for (int c = 0; c < 5; c++) W5[r][c] = 0.0f;

    const float* fp = filt + (size_t)b * 16 * HW + pix;
#pragma unroll
    for (int j = 0; j < 4; j++) {
#pragma unroll
        for (int i = 0; i < 4; i++) {
            float w3 = fp[(j * 4 + i) * HW];
            W5[j][i]         += wa * w3;
            W5[j][i + 1]     += wb * w3;
            W5[j + 1][i]     += wc * w3;
            W5[j + 1][i + 1] += wd * w3;
        }
    }
#pragma unroll
    for (int r = 0; r < 5; r++)
#pragma unroll
        for (int c = 0; c < 5; c++) W5[r][c] *= mf;

    int cx[5], ry[5];
#pragma unroll
    for (int k = 0; k < 5; k++) {
        cx[k] = min(max(ixL + k, 0), WW - 1);
        ry[k] = min(max(iyT + k, 0), HH - 1);
    }

    float ax = 0.0f, ay = 0.0f, az = 0.0f;
#pragma unroll
    for (int r = 0; r < 5; r++) {
        const float4* rowp = pk + ((size_t)(b * HH + ry[r])) * WW;
#pragma unroll
        for (int c = 0; c < 5; c++) {
            float4 v = rowp[cx[c]];
            float w = W5[r][c];
            ax = fmaf(w, v.x, ax);
            ay = fmaf(w, v.y, ay);
            az = fmaf(w, v.z, az);
        }
    }

    float* ob = out + (size_t)b * 3 * HW + pix;
    ob[0]      = ax;
    ob[HW]     = ay;
    ob[2 * HW] = az;
}

extern "C" void kernel_launch(void* const* d_in, const int* in_sizes, int n_in,
                              void* d_out, int out_size, void* d_ws, size_t ws_size,
                              hipStream_t stream) {
    const float* img  = (const float*)d_in[0];
    const float* flow = (const float*)d_in[1];
    const float* filt = (const float*)d_in[2];
    float* out = (float*)d_out;
    float4* pk = (float4*)d_ws;       // needs B*HW*16 bytes = 33.4 MB

    int n = BB * HW;                  // 2,088,960
    int blocks = (n + 255) / 256;     // 8160
    repack_img_kernel<<<blocks, 256, 0, stream>>>(img, pk);
    filt_interp_kernel<<<blocks, 256, 0, stream>>>(pk, flow, filt, out);
}

// Round 3
// 228.440 us; speedup vs baseline: 1.3236x; 1.2553x over previous
//
#include <hip/hip_runtime.h>

// FilterInterpolation, round 3.
// out[b,ch,y,x] = mask * sum_{r,c in 5x5} W5[r][c] * img[b,ch, clip(iyT+r), clip(ixL+c)]
// (exact regrouping of the 16 taps x 4 bilinear corners onto the 5x5 grid).
//
// R2 was bound by L1/TA cacheline transactions: i.i.d. per-pixel flow makes
// each of the 25 gathers touch ~45 cachelines per wave. R3 stages a clipped,
// channel-interleaved 16x76 float4 tile in LDS (stride 77 to break bank
// periodicity) per 64x4-pixel block; gathers become ds_read_b128. Rare
// out-of-tile threads (|flow| tail) fall back to global gathers (execz-skipped
// for nearly all waves). Repack kernel deleted.

#define BB 4
#define HH 544
#define WW 960
#define HW (HH * WW)

#define BX 64          // block pixels in x
#define BY 4           // block pixels in y
#define MARG 6         // tile margin
#define TW (BX + 2 * MARG)   // 76 tile cols
#define TH (BY + 2 * MARG)   // 16 tile rows
#define TS (TW + 1)          // 77: LDS row stride (float4 units)

__global__ __launch_bounds__(256) void filt_interp_kernel(
    const float* __restrict__ img,   // (B,3,H,W)
    const float* __restrict__ flow,  // (B,2,H,W)
    const float* __restrict__ filt,  // (B,16,H,W)
    float* __restrict__ out)         // (B,3,H,W)
{
    __shared__ float4 tile[TH * TS];   // 19,712 B

    const int tid = threadIdx.x;
    const int x0 = blockIdx.x * BX;
    const int y0 = blockIdx.y * BY;
    const int b  = blockIdx.z;
    const int tx0 = x0 - MARG;
    const int ty0 = y0 - MARG;

    // ---- stage clipped, channel-interleaved tile ----
    const float* ibase = img + (size_t)b * 3 * HW;
    for (int li = tid; li < TH * TW; li += 256) {
        int vr = li / TW;
        int vc = li - vr * TW;
        int gy = min(max(ty0 + vr, 0), HH - 1);
        int gx = min(max(tx0 + vc, 0), WW - 1);
        const float* ip = ibase + gy * WW + gx;
        float4 v;
        v.x = ip[0];
        v.y = ip[HW];
        v.z = ip[2 * HW];
        v.w = 0.0f;
        tile[vr * TS + vc] = v;
    }
    __syncthreads();

    // ---- per-pixel work ----
    const int lx = tid & 63;          // wave = one row of 64 pixels
    const int ly = tid >> 6;
    const int x = x0 + lx;
    const int y = y0 + ly;
    const int pix = y * WW + x;

    float fx = flow[(b * 2 + 0) * HW + pix];
    float fy = flow[(b * 2 + 1) * HW + pix];
    float x2 = (float)x + fx;
    float y2 = (float)y + fy;
    bool m = (x2 >= 0.0f) && (y2 >= 0.0f) &&
             (x2 <= (float)(WW - 1)) && (y2 <= (float)(HH - 1)) &&
             (fabsf(fx) < (float)WW * 0.5f) && (fabsf(fy) < (float)HH * 0.5f);
    float x2c = fminf(fmaxf(x2, 0.0f), (float)(WW - 1));
    float y2c = fminf(fmaxf(y2, 0.0f), (float)(HH - 1));
    int ix = (int)floorf(x2c);
    int iy = (int)floorf(y2c);
    float alpha = x2c - (float)ix;
    float beta  = y2c - (float)iy;
    int ixL = ix - 1;   // ix + 1 - fs/2
    int iyT = iy - 1;
    float wa = (1.0f - alpha) * (1.0f - beta);
    float wb = alpha * (1.0f - beta);
    float wc = (1.0f - alpha) * beta;
    float wd = alpha * beta;
    float mf = m ? 1.0f : 0.0f;

    // Build 5x5 combined weights (mask folded in).
    float W5[5][5];
#pragma unroll
    for (int r = 0; r < 5; r++)
#pragma unroll
        for (int c = 0; c < 5; c++) W5[r][c] = 0.0f;

    const float* fp = filt + (size_t)b * 16 * HW + pix;
#pragma unroll
    for (int j = 0; j < 4; j++) {
#pragma unroll
        for (int i = 0; i < 4; i++) {
            float w3 = fp[(j * 4 + i) * HW];
            W5[j][i]         += wa * w3;
            W5[j][i + 1]     += wb * w3;
            W5[j + 1][i]     += wc * w3;
            W5[j + 1][i + 1] += wd * w3;
        }
    }
#pragma unroll
    for (int r = 0; r < 5; r++)
#pragma unroll
        for (int c = 0; c < 5; c++) W5[r][c] *= mf;

    float ax = 0.0f, ay = 0.0f, az = 0.0f;

    // In-tile test (ix,iy are clip-derived so already within [0,W-1]x[0,H-1]).
    bool ok = (iyT >= ty0) && (iyT + 4 <= ty0 + TH - 1) &&
              (ixL >= tx0) && (ixL + 4 <= tx0 + TW - 1);

    if (ok) {
        int base = (iyT - ty0) * TS + (ixL - tx0);
#pragma unroll
        for (int r = 0; r < 5; r++) {
#pragma unroll
            for (int c = 0; c < 5; c++) {
                float4 v = tile[base + r * TS + c];
                float w = W5[r][c];
                ax = fmaf(w, v.x, ax);
                ay = fmaf(w, v.y, ay);
                az = fmaf(w, v.z, az);
            }
        }
    } else {
        // Rare fallback: direct clipped global gathers (exact same values).
        int cx[5], ry[5];
#pragma unroll
        for (int k = 0; k < 5; k++) {
            cx[k] = min(max(ixL + k, 0), WW - 1);
            ry[k] = min(max(iyT + k, 0), HH - 1);
        }
#pragma unroll
        for (int r = 0; r < 5; r++) {
            const float* rowp = ibase + ry[r] * WW;
#pragma unroll
            for (int c = 0; c < 5; c++) {
                float w = W5[r][c];
                const float* p = rowp + cx[c];
                ax = fmaf(w, p[0], ax);
                ay = fmaf(w, p[HW], ay);
                az = fmaf(w, p[2 * HW], az);
            }
        }
    }

    float* ob = out + (size_t)b * 3 * HW + pix;
    ob[0]      = ax;
    ob[HW]     = ay;
    ob[2 * HW] = az;
}

extern "C" void kernel_launch(void* const* d_in, const int* in_sizes, int n_in,
                              void* d_out, int out_size, void* d_ws, size_t ws_size,
                              hipStream_t stream) {
    const float* img  = (const float*)d_in[0];
    const float* flow = (const float*)d_in[1];
    const float* filt = (const float*)d_in[2];
    float* out = (float*)d_out;

    dim3 grid(WW / BX, HH / BY, BB);   // 15 x 136 x 4 = 8160 blocks
    filt_interp_kernel<<<grid, 256, 0, stream>>>(img, flow, filt, out);
}

// Round 4
// 228.234 us; speedup vs baseline: 1.3248x; 1.0009x over previous
//
#include <hip/hip_runtime.h>

// FilterInterpolation, round 4.
// out[b,ch,y,x] = mask * sum_{r,c in 5x5} W5[r][c] * img[b,ch, clip(iyT+r), clip(ixL+c)]
// (exact regrouping of the 16 taps x 4 bilinear corners onto the 5x5 grid).
//
// R3 (LDS-staged gathers) ~75 us. R4: BY=8 tile with 2 pixels/thread
// (staging amortized 14.25 -> 8.9 img loads/pixel, 2x ILP), mask folded into
// the 4 bilinear weights, nontemporal loads for stream-once filt/flow and
// nontemporal stores for out (preserve L2 for img tiles).

#define BB 4
#define HH 544
#define WW 960
#define HW (HH * WW)

#define BX 64          // block pixels in x
#define BY 8           // block pixels in y (2 per thread)
#define MARG 6         // tile margin
#define TW (BX + 2 * MARG)   // 76 tile cols
#define TH (BY + 2 * MARG)   // 20 tile rows
#define TS (TW + 1)          // 77: LDS row stride (float4 units)

__global__ __launch_bounds__(256) void filt_interp_kernel(
    const float* __restrict__ img,   // (B,3,H,W)
    const float* __restrict__ flow,  // (B,2,H,W)
    const float* __restrict__ filt,  // (B,16,H,W)
    float* __restrict__ out)         // (B,3,H,W)
{
    __shared__ float4 tile[TH * TS];   // 24,640 B -> 6 blocks/CU LDS cap

    const int tid = threadIdx.x;
    const int x0 = blockIdx.x * BX;
    const int y0 = blockIdx.y * BY;
    const int b  = blockIdx.z;
    const int tx0 = x0 - MARG;
    const int ty0 = y0 - MARG;

    // ---- stage clipped, channel-interleaved tile (coalesced rows) ----
    const float* ibase = img + (size_t)b * 3 * HW;
    for (int li = tid; li < TH * TW; li += 256) {
        int vr = li / TW;
        int vc = li - vr * TW;
        int gy = min(max(ty0 + vr, 0), HH - 1);
        int gx = min(max(tx0 + vc, 0), WW - 1);
        const float* ip = ibase + gy * WW + gx;
        float4 v;
        v.x = ip[0];
        v.y = ip[HW];
        v.z = ip[2 * HW];
        v.w = 0.0f;
        tile[vr * TS + vc] = v;
    }
    __syncthreads();

    const int lx = tid & 63;          // wave = one row of 64 pixels
    const int ly = tid >> 6;          // 0..3
    const int x = x0 + lx;

#pragma unroll
    for (int pp = 0; pp < 2; pp++) {
        const int y = y0 + ly + pp * 4;
        const int pix = y * WW + x;

        float fx = __builtin_nontemporal_load(flow + (b * 2 + 0) * HW + pix);
        float fy = __builtin_nontemporal_load(flow + (b * 2 + 1) * HW + pix);
        float x2 = (float)x + fx;
        float y2 = (float)y + fy;
        bool m = (x2 >= 0.0f) && (y2 >= 0.0f) &&
                 (x2 <= (float)(WW - 1)) && (y2 <= (float)(HH - 1)) &&
                 (fabsf(fx) < (float)WW * 0.5f) && (fabsf(fy) < (float)HH * 0.5f);
        float x2c = fminf(fmaxf(x2, 0.0f), (float)(WW - 1));
        float y2c = fminf(fmaxf(y2, 0.0f), (float)(HH - 1));
        int ix = (int)floorf(x2c);
        int iy = (int)floorf(y2c);
        float alpha = x2c - (float)ix;
        float beta  = y2c - (float)iy;
        int ixL = ix - 1;   // ix + 1 - fs/2
        int iyT = iy - 1;
        float mf = m ? 1.0f : 0.0f;
        float wa = (1.0f - alpha) * (1.0f - beta) * mf;
        float wb = alpha * (1.0f - beta) * mf;
        float wc = (1.0f - alpha) * beta * mf;
        float wd = alpha * beta * mf;

        // Build 5x5 combined weights (mask pre-folded via wa..wd).
        float W5[5][5];
#pragma unroll
        for (int r = 0; r < 5; r++)
#pragma unroll
            for (int c = 0; c < 5; c++) W5[r][c] = 0.0f;

        const float* fp = filt + (size_t)b * 16 * HW + pix;
#pragma unroll
        for (int j = 0; j < 4; j++) {
#pragma unroll
            for (int i = 0; i < 4; i++) {
                float w3 = __builtin_nontemporal_load(fp + (j * 4 + i) * HW);
                W5[j][i]         += wa * w3;
                W5[j][i + 1]     += wb * w3;
                W5[j + 1][i]     += wc * w3;
                W5[j + 1][i + 1] += wd * w3;
            }
        }

        float ax = 0.0f, ay = 0.0f, az = 0.0f;

        bool ok = (iyT >= ty0) && (iyT + 4 <= ty0 + TH - 1) &&
                  (ixL >= tx0) && (ixL + 4 <= tx0 + TW - 1);

        if (ok) {
            int base = (iyT - ty0) * TS + (ixL - tx0);
#pragma unroll
            for (int r = 0; r < 5; r++) {
#pragma unroll
                for (int c = 0; c < 5; c++) {
                    float4 v = tile[base + r * TS + c];
                    float w = W5[r][c];
                    ax = fmaf(w, v.x, ax);
                    ay = fmaf(w, v.y, ay);
                    az = fmaf(w, v.z, az);
                }
            }
        } else {
            // Rare fallback (|flow| tail): direct clipped global gathers.
            int cx[5], ry[5];
#pragma unroll
            for (int k = 0; k < 5; k++) {
                cx[k] = min(max(ixL + k, 0), WW - 1);
                ry[k] = min(max(iyT + k, 0), HH - 1);
            }
#pragma unroll
            for (int r = 0; r < 5; r++) {
                const float* rowp = ibase + ry[r] * WW;
#pragma unroll
                for (int c = 0; c < 5; c++) {
                    float w = W5[r][c];
                    const float* p = rowp + cx[c];
                    ax = fmaf(w, p[0], ax);
                    ay = fmaf(w, p[HW], ay);
                    az = fmaf(w, p[2 * HW], az);
                }
            }
        }

        float* ob = out + (size_t)b * 3 * HW + pix;
        __builtin_nontemporal_store(ax, ob);
        __builtin_nontemporal_store(ay, ob + HW);
        __builtin_nontemporal_store(az, ob + 2 * HW);
    }
}

extern "C" void kernel_launch(void* const* d_in, const int* in_sizes, int n_in,
                              void* d_out, int out_size, void* d_ws, size_t ws_size,
                              hipStream_t stream) {
    const float* img  = (const float*)d_in[0];
    const float* flow = (const float*)d_in[1];
    const float* filt = (const float*)d_in[2];
    float* out = (float*)d_out;

    dim3 grid(WW / BX, HH / BY, BB);   // 15 x 68 x 4 = 4080 blocks
    filt_interp_kernel<<<grid, 256, 0, stream>>>(img, flow, filt, out);
}

// Round 6
// 224.538 us; speedup vs baseline: 1.3466x; 1.0165x over previous
//
#include <hip/hip_runtime.h>

// FilterInterpolation, round 5b (R5 with compile fix: clang ext_vector_type
// for nontemporal builtins — HIP float2 is a class and is rejected).
// out[b,ch,y,x] = mask * sum_{r,c in 5x5} W5[r][c] * img[b,ch, clip(iyT+r), clip(ixL+c)]
//
// R3/R4 both ~74 us kernel; insensitive to staging/occupancy/ILP -> bound by
// filt-stream miss chains / VMEM issue. R5: each thread owns an x-ADJACENT
// pixel pair; filt/flow/out accesses become dwordx2 (16 filt loads/thread
// instead of 32), all issued up-front for deep MLP.

#define BB 4
#define HH 544
#define WW 960
#define HW (HH * WW)

#define BX 64          // block pixels in x
#define BY 8           // block pixels in y
#define MARG 6         // tile margin
#define TW (BX + 2 * MARG)   // 76 tile cols
#define TH (BY + 2 * MARG)   // 20 tile rows
#define TS (TW + 1)          // 77: LDS row stride (float4 units)

typedef float v2f __attribute__((ext_vector_type(2)));

__global__ __launch_bounds__(256) void filt_interp_kernel(
    const float* __restrict__ img,   // (B,3,H,W)
    const float* __restrict__ flow,  // (B,2,H,W)
    const float* __restrict__ filt,  // (B,16,H,W)
    float* __restrict__ out)         // (B,3,H,W)
{
    __shared__ float4 tile[TH * TS];   // 24,640 B -> 6 blocks/CU LDS cap

    const int tid = threadIdx.x;
    const int x0 = blockIdx.x * BX;
    const int y0 = blockIdx.y * BY;
    const int b  = blockIdx.z;
    const int tx0 = x0 - MARG;
    const int ty0 = y0 - MARG;

    // ---- stage clipped, channel-interleaved tile (coalesced rows) ----
    const float* ibase = img + (size_t)b * 3 * HW;
    for (int li = tid; li < TH * TW; li += 256) {
        int vr = li / TW;
        int vc = li - vr * TW;
        int gy = min(max(ty0 + vr, 0), HH - 1);
        int gx = min(max(tx0 + vc, 0), WW - 1);
        const float* ip = ibase + gy * WW + gx;
        float4 v;
        v.x = ip[0];
        v.y = ip[HW];
        v.z = ip[2 * HW];
        v.w = 0.0f;
        tile[vr * TS + vc] = v;
    }
    __syncthreads();

    // ---- per-thread: one x-adjacent pixel pair ----
    const int xp = tid & 31;          // x-pair index within row
    const int yr = tid >> 5;          // 0..7
    const int x = x0 + 2 * xp;
    const int y = y0 + yr;
    const int pix = y * WW + x;

    // Batch ALL stream loads up-front (independent -> deep MLP).
    v2f fxp = __builtin_nontemporal_load((const v2f*)(flow + (size_t)(b * 2 + 0) * HW + pix));
    v2f fyp = __builtin_nontemporal_load((const v2f*)(flow + (size_t)(b * 2 + 1) * HW + pix));
    const float* fp = filt + (size_t)b * 16 * HW + pix;
    v2f w3p[16];
#pragma unroll
    for (int t = 0; t < 16; t++)
        w3p[t] = __builtin_nontemporal_load((const v2f*)(fp + (size_t)t * HW));

    float res[2][3];

#pragma unroll
    for (int k = 0; k < 2; k++) {
        const int xk = x + k;
        float fx = fxp[k];
        float fy = fyp[k];
        float x2 = (float)xk + fx;
        float y2 = (float)y + fy;
        bool m = (x2 >= 0.0f) && (y2 >= 0.0f) &&
                 (x2 <= (float)(WW - 1)) && (y2 <= (float)(HH - 1)) &&
                 (fabsf(fx) < (float)WW * 0.5f) && (fabsf(fy) < (float)HH * 0.5f);
        float x2c = fminf(fmaxf(x2, 0.0f), (float)(WW - 1));
        float y2c = fminf(fmaxf(y2, 0.0f), (float)(HH - 1));
        int ix = (int)floorf(x2c);
        int iy = (int)floorf(y2c);
        float alpha = x2c - (float)ix;
        float beta  = y2c - (float)iy;
        int ixL = ix - 1;   // ix + 1 - fs/2
        int iyT = iy - 1;
        float mf = m ? 1.0f : 0.0f;
        float wa = (1.0f - alpha) * (1.0f - beta) * mf;
        float wb = alpha * (1.0f - beta) * mf;
        float wc = (1.0f - alpha) * beta * mf;
        float wd = alpha * beta * mf;

        // Build 5x5 combined weights (mask pre-folded via wa..wd).
        float W5[5][5];
#pragma unroll
        for (int r = 0; r < 5; r++)
#pragma unroll
            for (int c = 0; c < 5; c++) W5[r][c] = 0.0f;

#pragma unroll
        for (int j = 0; j < 4; j++) {
#pragma unroll
            for (int i = 0; i < 4; i++) {
                float w3 = w3p[j * 4 + i][k];
                W5[j][i]         += wa * w3;
                W5[j][i + 1]     += wb * w3;
                W5[j + 1][i]     += wc * w3;
                W5[j + 1][i + 1] += wd * w3;
            }
        }

        float ax = 0.0f, ay = 0.0f, az = 0.0f;

        bool ok = (iyT >= ty0) && (iyT + 4 <= ty0 + TH - 1) &&
                  (ixL >= tx0) && (ixL + 4 <= tx0 + TW - 1);

        if (ok) {
            int base = (iyT - ty0) * TS + (ixL - tx0);
#pragma unroll
            for (int r = 0; r < 5; r++) {
#pragma unroll
                for (int c = 0; c < 5; c++) {
                    float4 v = tile[base + r * TS + c];
                    float w = W5[r][c];
                    ax = fmaf(w, v.x, ax);
                    ay = fmaf(w, v.y, ay);
                    az = fmaf(w, v.z, az);
                }
            }
        } else {
            // Rare fallback (|flow| tail): direct clipped global gathers.
            int cx[5], ry[5];
#pragma unroll
            for (int q = 0; q < 5; q++) {
                cx[q] = min(max(ixL + q, 0), WW - 1);
                ry[q] = min(max(iyT + q, 0), HH - 1);
            }
#pragma unroll
            for (int r = 0; r < 5; r++) {
                const float* rowp = ibase + ry[r] * WW;
#pragma unroll
                for (int c = 0; c < 5; c++) {
                    float w = W5[r][c];
                    const float* p = rowp + cx[c];
                    ax = fmaf(w, p[0], ax);
                    ay = fmaf(w, p[HW], ay);
                    az = fmaf(w, p[2 * HW], az);
                }
            }
        }

        res[k][0] = ax;
        res[k][1] = ay;
        res[k][2] = az;
    }

    float* ob = out + (size_t)b * 3 * HW + pix;
    v2f s0 = {res[0][0], res[1][0]};
    v2f s1 = {res[0][1], res[1][1]};
    v2f s2 = {res[0][2], res[1][2]};
    __builtin_nontemporal_store(s0, (v2f*)(ob));
    __builtin_nontemporal_store(s1, (v2f*)(ob + HW));
    __builtin_nontemporal_store(s2, (v2f*)(ob + 2 * HW));
}

extern "C" void kernel_launch(void* const* d_in, const int* in_sizes, int n_in,
                              void* d_out, int out_size, void* d_ws, size_t ws_size,
                              hipStream_t stream) {
    const float* img  = (const float*)d_in[0];
    const float* flow = (const float*)d_in[1];
    const float* filt = (const float*)d_in[2];
    float* out = (float*)d_out;

    dim3 grid(WW / BX, HH / BY, BB);   // 15 x 68 x 4 = 4080 blocks
    filt_interp_kernel<<<grid, 256, 0, stream>>>(img, flow, filt, out);
}

// Round 7
// 222.560 us; speedup vs baseline: 1.3586x; 1.0089x over previous
//
#include <hip/hip_runtime.h>

// FilterInterpolation, round 7.
// out[b,ch,y,x] = mask * sum_{r,c in 5x5} W5[r][c] * img[b,ch, clip(iyT+r), clip(ixL+c)]
// (exact regrouping of the 16 taps x 4 bilinear corners onto the 5x5 grid).
//
// R6 analysis: float4-strided LDS tile aliases every gather onto 8 bank-quads
// (bank = 4*(f%8)+k) -> ~8-way conflicts, ~40 cyc per ds_read_b128, ~50 us of
// LDS serialization. R7: float3-packed tile, word stride 3 (gcd(3,32)=1 ->
// gathers spread across all 32 banks, ~2-way = free), row stride 229 words
// (odd). Tile 18.3 KB -> 8 blocks/CU. Streams stay dwordx2 pixel-pairs.

#define BB 4
#define HH 544
#define WW 960
#define HW (HH * WW)

#define BX 64          // block pixels in x
#define BY 8           // block pixels in y
#define MARG 6         // tile margin
#define TW (BX + 2 * MARG)   // 76 tile cols
#define TH (BY + 2 * MARG)   // 20 tile rows
#define TSW (TW * 3 + 1)     // 229 words: LDS row stride (odd -> no row alias)

typedef float v2f __attribute__((ext_vector_type(2)));

__global__ __launch_bounds__(256) void filt_interp_kernel(
    const float* __restrict__ img,   // (B,3,H,W)
    const float* __restrict__ flow,  // (B,2,H,W)
    const float* __restrict__ filt,  // (B,16,H,W)
    float* __restrict__ out)         // (B,3,H,W)
{
    __shared__ float tile[TH * TSW];   // 18,320 B -> 8 blocks/CU

    const int tid = threadIdx.x;
    const int x0 = blockIdx.x * BX;
    const int y0 = blockIdx.y * BY;
    const int b  = blockIdx.z;
    const int tx0 = x0 - MARG;
    const int ty0 = y0 - MARG;

    // ---- stage clipped, channel-packed (float3) tile ----
    const float* ibase = img + (size_t)b * 3 * HW;
    for (int li = tid; li < TH * TW; li += 256) {
        int vr = li / TW;
        int vc = li - vr * TW;
        int gy = min(max(ty0 + vr, 0), HH - 1);
        int gx = min(max(tx0 + vc, 0), WW - 1);
        const float* ip = ibase + gy * WW + gx;
        float* tp = tile + vr * TSW + vc * 3;
        tp[0] = ip[0];
        tp[1] = ip[HW];
        tp[2] = ip[2 * HW];
    }
    __syncthreads();

    // ---- per-thread: one x-adjacent pixel pair ----
    const int xp = tid & 31;          // x-pair index within row
    const int yr = tid >> 5;          // 0..7
    const int x = x0 + 2 * xp;
    const int y = y0 + yr;
    const int pix = y * WW + x;

    // Batch all stream loads up-front (independent -> deep MLP).
    v2f fxp = __builtin_nontemporal_load((const v2f*)(flow + (size_t)(b * 2 + 0) * HW + pix));
    v2f fyp = __builtin_nontemporal_load((const v2f*)(flow + (size_t)(b * 2 + 1) * HW + pix));
    const float* fp = filt + (size_t)b * 16 * HW + pix;
    v2f w3p[16];
#pragma unroll
    for (int t = 0; t < 16; t++)
        w3p[t] = __builtin_nontemporal_load((const v2f*)(fp + (size_t)t * HW));

    float res[2][3];

#pragma unroll
    for (int k = 0; k < 2; k++) {
        const int xk = x + k;
        float fx = fxp[k];
        float fy = fyp[k];
        float x2 = (float)xk + fx;
        float y2 = (float)y + fy;
        bool m = (x2 >= 0.0f) && (y2 >= 0.0f) &&
                 (x2 <= (float)(WW - 1)) && (y2 <= (float)(HH - 1)) &&
                 (fabsf(fx) < (float)WW * 0.5f) && (fabsf(fy) < (float)HH * 0.5f);
        float x2c = fminf(fmaxf(x2, 0.0f), (float)(WW - 1));
        float y2c = fminf(fmaxf(y2, 0.0f), (float)(HH - 1));
        int ix = (int)floorf(x2c);
        int iy = (int)floorf(y2c);
        float alpha = x2c - (float)ix;
        float beta  = y2c - (float)iy;
        int ixL = ix - 1;   // ix + 1 - fs/2
        int iyT = iy - 1;
        float mf = m ? 1.0f : 0.0f;
        float wa = (1.0f - alpha) * (1.0f - beta) * mf;
        float wb = alpha * (1.0f - beta) * mf;
        float wc = (1.0f - alpha) * beta * mf;
        float wd = alpha * beta * mf;

        // Build 5x5 combined weights (mask pre-folded via wa..wd).
        float W5[5][5];
#pragma unroll
        for (int r = 0; r < 5; r++)
#pragma unroll
            for (int c = 0; c < 5; c++) W5[r][c] = 0.0f;

#pragma unroll
        for (int j = 0; j < 4; j++) {
#pragma unroll
            for (int i = 0; i < 4; i++) {
                float w3 = w3p[j * 4 + i][k];
                W5[j][i]         += wa * w3;
                W5[j][i + 1]     += wb * w3;
                W5[j + 1][i]     += wc * w3;
                W5[j + 1][i + 1] += wd * w3;
            }
        }

        float ax = 0.0f, ay = 0.0f, az = 0.0f;

        bool ok = (iyT >= ty0) && (iyT + 4 <= ty0 + TH - 1) &&
                  (ixL >= tx0) && (ixL + 4 <= tx0 + TW - 1);

        if (ok) {
            int base = (iyT - ty0) * TSW + (ixL - tx0) * 3;
#pragma unroll
            for (int r = 0; r < 5; r++) {
#pragma unroll
                for (int c = 0; c < 5; c++) {
                    const float* tp = tile + base + r * TSW + c * 3;
                    float w = W5[r][c];
                    ax = fmaf(w, tp[0], ax);
                    ay = fmaf(w, tp[1], ay);
                    az = fmaf(w, tp[2], az);
                }
            }
        } else {
            // Rare fallback (|flow| tail): direct clipped global gathers.
            int cx[5], ry[5];
#pragma unroll
            for (int q = 0; q < 5; q++) {
                cx[q] = min(max(ixL + q, 0), WW - 1);
                ry[q] = min(max(iyT + q, 0), HH - 1);
            }
#pragma unroll
            for (int r = 0; r < 5; r++) {
                const float* rowp = ibase + ry[r] * WW;
#pragma unroll
                for (int c = 0; c < 5; c++) {
                    float w = W5[r][c];
                    const float* p = rowp + cx[c];
                    ax = fmaf(w, p[0], ax);
                    ay = fmaf(w, p[HW], ay);
                    az = fmaf(w, p[2 * HW], az);
                }
            }
        }

        res[k][0] = ax;
        res[k][1] = ay;
        res[k][2] = az;
    }

    float* ob = out + (size_t)b * 3 * HW + pix;
    v2f s0 = {res[0][0], res[1][0]};
    v2f s1 = {res[0][1], res[1][1]};
    v2f s2 = {res[0][2], res[1][2]};
    __builtin_nontemporal_store(s0, (v2f*)(ob));
    __builtin_nontemporal_store(s1, (v2f*)(ob + HW));
    __builtin_nontemporal_store(s2, (v2f*)(ob + 2 * HW));
}

extern "C" void kernel_launch(void* const* d_in, const int* in_sizes, int n_in,
                              void* d_out, int out_size, void* d_ws, size_t ws_size,
                              hipStream_t stream) {
    const float* img  = (const float*)d_in[0];
    const float* flow = (const float*)d_in[1];
    const float* filt = (const float*)d_in[2];
    float* out = (float*)d_out;

    dim3 grid(WW / BX, HH / BY, BB);   // 15 x 68 x 4 = 4080 blocks
    filt_interp_kernel<<<grid, 256, 0, stream>>>(img, flow, filt, out);
}